// Round 4
// baseline (465.792 us; speedup 1.0000x reference)
//
#include <hip/hip_runtime.h>
#include <hip/hip_bf16.h>

#define H 10
#define HP 16          // padded hidden (DPP row width)
#define T_LEN 2048
#define BATCH 8192

// ---------------------------------------------------------------------------
// Kernel 1: Bp = expm(triu(A,1) - triu(A,1)^T) in fp64, PADDED to 16x16
// (zeros outside 10x10), fp32 into ws. Fixed scaling s=8, 16 Taylor terms,
// 8 squarings.
// ---------------------------------------------------------------------------
__global__ void expm_kernel(const float* __restrict__ A, float* __restrict__ Bout) {
    __shared__ double S[H][H];
    __shared__ double P[H][H];
    __shared__ double E[H][H];
    const int tid = threadIdx.x;
    const int i = tid / H, j = tid % H;
    if (tid < H * H) {
        double a = 0.0;
        if (i < j) a = (double)A[i * H + j];
        else if (i > j) a = -(double)A[j * H + i];
        a *= (1.0 / 256.0);
        S[i][j] = a;
        P[i][j] = a;
        E[i][j] = (i == j ? 1.0 : 0.0) + a;
    }
    __syncthreads();
    for (int k = 2; k <= 16; ++k) {
        double acc = 0.0;
        if (tid < H * H) {
            for (int m = 0; m < H; ++m) acc += P[i][m] * S[m][j];
            acc *= (1.0 / (double)k);
        }
        __syncthreads();
        if (tid < H * H) { P[i][j] = acc; E[i][j] += acc; }
        __syncthreads();
    }
    for (int rr = 0; rr < 8; ++rr) {
        double acc = 0.0;
        if (tid < H * H) {
            for (int m = 0; m < H; ++m) acc += E[i][m] * E[m][j];
        }
        __syncthreads();
        if (tid < H * H) E[i][j] = acc;
        __syncthreads();
    }
    // padded 16x16 write
    for (int idx = tid; idx < HP * HP; idx += blockDim.x) {
        const int i2 = idx / HP, j2 = idx % HP;
        Bout[idx] = (i2 < H && j2 < H) ? (float)E[i2][j2] : 0.0f;
    }
}

// ---------------------------------------------------------------------------
// Kernel 2: DPP-exchange recurrence. One batch per 16-lane row; lane r owns
// h[r] (lanes 10..15 pinned to h=0 via zeroed weights). The matvec is
// 19 FMAs whose h-operands arrive via DPP row_shr:k / row_shl:k
// (row_shr:k => lane n reads lane n-k; bound_ctrl=1 zero-fills OOB lanes,
// so dead terms are exact +0). Zero DS-pipe traffic in the hot loop.
// 8192 batches / 4 rows per wave = 2048 waves -> 2 waves/SIMD.
// ---------------------------------------------------------------------------

#define DPP_SHR(vbits, k) \
    __int_as_float(__builtin_amdgcn_update_dpp(0, (vbits), 0x110 + (k), 0xF, 0xF, true))
#define DPP_SHL(vbits, k) \
    __int_as_float(__builtin_amdgcn_update_dpp(0, (vbits), 0x100 + (k), 0xF, 0xF, true))

__global__ __launch_bounds__(256, 2)
void rnn_kernel(const float* __restrict__ x,
                const float* __restrict__ Bp,     // padded 16x16
                const float* __restrict__ Win,
                const float* __restrict__ bmod,
                const float* __restrict__ lW,
                const float* __restrict__ lb,
                float* __restrict__ out) {
    const int tid = threadIdx.x;
    const int r = tid & 15;                 // lane within row (owns h[r])
    const int g = tid >> 4;                 // group within block (0..15)
    const int bb = blockIdx.x * 16 + g;     // batch element

    // per-lane B coefficients:
    //   own:     Bp[r][r]
    //   BvS[k]:  Bp[r-k][r]  pairs with row_shr:k (source lane r-k)
    //   BvL[k]:  Bp[r+k][r]  pairs with row_shl:k (source lane r+k)
    // wrapped/OOB indices are harmless: DPP zero-fills those source lanes.
    const float Bown = Bp[r * HP + r];
    float BvS[10], BvL[10];
#pragma unroll
    for (int k = 1; k <= 9; ++k) {
        BvS[k] = Bp[((r - k) & 15) * HP + r];
        BvL[k] = Bp[((r + k) & 15) * HP + r];
    }
    const bool live = (r < H);
    const float w0 = live ? Win[r * 2 + 0] : 0.0f;
    const float w1 = live ? Win[r * 2 + 1] : 0.0f;
    const float bm = live ? bmod[r] : 0.0f;   // lanes 10..15: h stays exactly 0
    float h = 0.0f;

    const float4* __restrict__ xp4 =
        (const float4*)(x + (size_t)bb * (T_LEN * 2));  // shared across row

    float4 buf0 = xp4[0], buf1 = xp4[1], buf2 = xp4[2], buf3 = xp4[3];

    for (int t0 = 0; t0 < T_LEN; t0 += 8) {
        const float4 c0 = buf0, c1 = buf1, c2 = buf2, c3 = buf3;
        if (t0 + 8 < T_LEN) {
            const int base = (t0 + 8) >> 1;
            buf0 = xp4[base + 0];
            buf1 = xp4[base + 1];
            buf2 = xp4[base + 2];
            buf3 = xp4[base + 3];
        }
        float xs[16];
        xs[0] = c0.x; xs[1] = c0.y; xs[2]  = c0.z; xs[3]  = c0.w;
        xs[4] = c1.x; xs[5] = c1.y; xs[6]  = c1.z; xs[7]  = c1.w;
        xs[8] = c2.x; xs[9] = c2.y; xs[10] = c2.z; xs[11] = c2.w;
        xs[12] = c3.x; xs[13] = c3.y; xs[14] = c3.z; xs[15] = c3.w;

#pragma unroll
        for (int u = 0; u < 8; ++u) {
            const float x0 = xs[2 * u], x1 = xs[2 * u + 1];
            const int hbits = __float_as_int(h);
            // four independent accumulation chains
            float cA = x0 * w0;
            float cB = x1 * w1;
            float cC = h * Bown;
            float cD = DPP_SHR(hbits, 1) * BvS[1];
            cA = fmaf(DPP_SHR(hbits, 2), BvS[2], cA);
            cB = fmaf(DPP_SHR(hbits, 3), BvS[3], cB);
            cC = fmaf(DPP_SHR(hbits, 4), BvS[4], cC);
            cD = fmaf(DPP_SHR(hbits, 5), BvS[5], cD);
            cA = fmaf(DPP_SHR(hbits, 6), BvS[6], cA);
            cB = fmaf(DPP_SHR(hbits, 7), BvS[7], cB);
            cC = fmaf(DPP_SHR(hbits, 8), BvS[8], cC);
            cD = fmaf(DPP_SHR(hbits, 9), BvS[9], cD);
            cA = fmaf(DPP_SHL(hbits, 1), BvL[1], cA);
            cB = fmaf(DPP_SHL(hbits, 2), BvL[2], cB);
            cC = fmaf(DPP_SHL(hbits, 3), BvL[3], cC);
            cD = fmaf(DPP_SHL(hbits, 4), BvL[4], cD);
            cA = fmaf(DPP_SHL(hbits, 5), BvL[5], cA);
            cB = fmaf(DPP_SHL(hbits, 6), BvL[6], cB);
            cC = fmaf(DPP_SHL(hbits, 7), BvL[7], cC);
            cD = fmaf(DPP_SHL(hbits, 8), BvL[8], cD);
            cA = fmaf(DPP_SHL(hbits, 9), BvL[9], cA);
            const float acc = (cA + cB) + (cC + cD);

            const float az = fabsf(acc) + bm;
            const float rr2 = fmaxf(az, 0.0f);
            h = __builtin_copysignf(rr2, acc);
        }
    }

    // epilogue (once): LDS exchange of final h, then the 10x10 projection
    __shared__ float hsh[16][17];
    hsh[g][r] = h;
    __syncthreads();
    if (live) {
        float acc = lb[r];
#pragma unroll
        for (int jj = 0; jj < H; ++jj)
            acc = fmaf(hsh[g][jj], lW[r * H + jj], acc);
        out[(size_t)bb * H + r] = acc;
    }
}

extern "C" void kernel_launch(void* const* d_in, const int* in_sizes, int n_in,
                              void* d_out, int out_size, void* d_ws, size_t ws_size,
                              hipStream_t stream) {
    const float* inputs = (const float*)d_in[0];  // [8192, 2048, 2]
    const float* A      = (const float*)d_in[1];  // [10, 10]
    const float* W_in   = (const float*)d_in[2];  // [10, 2]
    const float* b_mod  = (const float*)d_in[3];  // [10]
    const float* lin_W  = (const float*)d_in[4];  // [10, 10]
    const float* lin_b  = (const float*)d_in[5];  // [10]
    float* out = (float*)d_out;                   // [8192, 10]
    float* Bpad = (float*)d_ws;                   // 256 floats scratch

    expm_kernel<<<1, 128, 0, stream>>>(A, Bpad);
    rnn_kernel<<<BATCH / 16, 256, 0, stream>>>(inputs, Bpad, W_in, b_mod,
                                               lin_W, lin_b, out);
}

// Round 6
// 379.259 us; speedup vs baseline: 1.2282x; 1.2282x over previous
//
#include <hip/hip_runtime.h>
#include <hip/hip_bf16.h>

#define H 10
#define HP 16          // padded hidden (MFMA tile dim)
#define T_LEN 2048
#define BATCH 8192

typedef _Float16 h4_t __attribute__((ext_vector_type(4)));
typedef __fp16   p2_t __attribute__((ext_vector_type(2)));  // cvt_pkrtz result type
typedef float    f4_t __attribute__((ext_vector_type(4)));

// ---------------------------------------------------------------------------
// Kernel 1: Bp = expm(triu(A,1) - triu(A,1)^T) in fp64, PADDED to 16x16
// (zeros outside 10x10), fp32 into ws. Fixed scaling s=8, 16 Taylor terms,
// 8 squarings.
// ---------------------------------------------------------------------------
__global__ void expm_kernel(const float* __restrict__ A, float* __restrict__ Bout) {
    __shared__ double S[H][H];
    __shared__ double P[H][H];
    __shared__ double E[H][H];
    const int tid = threadIdx.x;
    const int i = tid / H, j = tid % H;
    if (tid < H * H) {
        double a = 0.0;
        if (i < j) a = (double)A[i * H + j];
        else if (i > j) a = -(double)A[j * H + i];
        a *= (1.0 / 256.0);
        S[i][j] = a;
        P[i][j] = a;
        E[i][j] = (i == j ? 1.0 : 0.0) + a;
    }
    __syncthreads();
    for (int k = 2; k <= 16; ++k) {
        double acc = 0.0;
        if (tid < H * H) {
            for (int m = 0; m < H; ++m) acc += P[i][m] * S[m][j];
            acc *= (1.0 / (double)k);
        }
        __syncthreads();
        if (tid < H * H) { P[i][j] = acc; E[i][j] += acc; }
        __syncthreads();
    }
    for (int rr = 0; rr < 8; ++rr) {
        double acc = 0.0;
        if (tid < H * H) {
            for (int m = 0; m < H; ++m) acc += E[i][m] * E[m][j];
        }
        __syncthreads();
        if (tid < H * H) E[i][j] = acc;
        __syncthreads();
    }
    for (int idx = tid; idx < HP * HP; idx += blockDim.x) {
        const int i2 = idx / HP, j2 = idx % HP;
        Bout[idx] = (i2 < H && j2 < H) ? (float)E[i2][j2] : 0.0f;
    }
}

// ---------------------------------------------------------------------------
// Kernel 2: MFMA fixed-point recurrence, zero exchange.
//   D = A.B + C with A := Bmat^T (constant, double-fp16), B-op := h in
//   [hidden][batch] layout, C := x-projection. For v_mfma_f32_16x16x16f16,
//   lane l (q=l>>4, m=l&15) holds:
//     A elem i  = A[row l&15][k=4q+i]   -> pack Bmat[4q+i][m]
//     B elem i  = B[k=4q+i][col l&15]   -> h[4q+i] of batch m
//     D reg  i  = D[row 4q+i][col l&15] -> z[n=4q+i] of batch m
//   D's (lane,reg)->index map == B-operand's map, so modrelu(D) feeds the
//   next step's B-operand with NO cross-lane movement. 16 batches/wave,
//   512 waves. Double-fp16: z = Bhi.hhi + Bhi.hlo + Blo.hhi (3 MFMAs),
//   per-step relative error ~2^-22.
// ---------------------------------------------------------------------------
__global__ __launch_bounds__(64)
void rnn_kernel(const float* __restrict__ x,
                const float* __restrict__ Bp,     // padded 16x16 fp32
                const float* __restrict__ Win,
                const float* __restrict__ bmod,
                const float* __restrict__ lW,
                const float* __restrict__ lb,
                float* __restrict__ out) {
    const int l = threadIdx.x;
    const int m = l & 15;                 // batch within tile / operand col
    const int q = l >> 4;                 // k/row quad
    const int n0 = q * 4;                 // hidden index base for regs
    const int batch = blockIdx.x * 16 + m;

    // A-operand (constant): a[i] = Bmat[4q+i][m], split into fp16 hi+lo
    h4_t a_hi, a_lo;
    f4_t w0v, w1v, bmv;
#pragma unroll
    for (int i = 0; i < 4; ++i) {
        const float bv = Bp[(n0 + i) * HP + m];
        const _Float16 hi = (_Float16)bv;
        a_hi[i] = hi;
        a_lo[i] = (_Float16)(bv - (float)hi);
        const int n = n0 + i;
        w0v[i] = (n < H) ? Win[n * 2 + 0] : 0.0f;
        w1v[i] = (n < H) ? Win[n * 2 + 1] : 0.0f;
        bmv[i] = (n < H) ? bmod[n] : 0.0f;
    }

    // recurrent state: h components (4q+i) of batch m, fp32 + fp16 hi/lo
    float hs0 = 0.0f, hs1 = 0.0f, hs2 = 0.0f, hs3 = 0.0f;
    h4_t b_hi = {0, 0, 0, 0};
    h4_t b_lo = {0, 0, 0, 0};

    const float4* __restrict__ xp4 =
        (const float4*)(x + (size_t)batch * (T_LEN * 2));

    float4 buf0 = xp4[0], buf1 = xp4[1], buf2 = xp4[2], buf3 = xp4[3];

    for (int t0 = 0; t0 < T_LEN; t0 += 8) {
        const float4 c0 = buf0, c1 = buf1, c2 = buf2, c3 = buf3;
        if (t0 + 8 < T_LEN) {
            const int base = (t0 + 8) >> 1;
            buf0 = xp4[base + 0];
            buf1 = xp4[base + 1];
            buf2 = xp4[base + 2];
            buf3 = xp4[base + 3];
        }
        float xs[16];
        xs[0] = c0.x; xs[1] = c0.y; xs[2]  = c0.z; xs[3]  = c0.w;
        xs[4] = c1.x; xs[5] = c1.y; xs[6]  = c1.z; xs[7]  = c1.w;
        xs[8] = c2.x; xs[9] = c2.y; xs[10] = c2.z; xs[11] = c2.w;
        xs[12] = c3.x; xs[13] = c3.y; xs[14] = c3.z; xs[15] = c3.w;

#pragma unroll
        for (int u = 0; u < 8; ++u) {
            const float x0 = xs[2 * u], x1 = xs[2 * u + 1];
            // C init = input projection for rows n0..n0+3, batch m
            f4_t c;
            c[0] = fmaf(x1, w1v[0], x0 * w0v[0]);
            c[1] = fmaf(x1, w1v[1], x0 * w0v[1]);
            c[2] = fmaf(x1, w1v[2], x0 * w0v[2]);
            c[3] = fmaf(x1, w1v[3], x0 * w0v[3]);

            f4_t acc = __builtin_amdgcn_mfma_f32_16x16x16f16(a_hi, b_hi, c, 0, 0, 0);
            acc = __builtin_amdgcn_mfma_f32_16x16x16f16(a_hi, b_lo, acc, 0, 0, 0);
            acc = __builtin_amdgcn_mfma_f32_16x16x16f16(a_lo, b_hi, acc, 0, 0, 0);

            // modrelu per element
            const float z0 = acc[0], z1 = acc[1], z2 = acc[2], z3 = acc[3];
            hs0 = __builtin_copysignf(fmaxf(fabsf(z0) + bmv[0], 0.0f), z0);
            hs1 = __builtin_copysignf(fmaxf(fabsf(z1) + bmv[1], 0.0f), z1);
            hs2 = __builtin_copysignf(fmaxf(fabsf(z2) + bmv[2], 0.0f), z2);
            hs3 = __builtin_copysignf(fmaxf(fabsf(z3) + bmv[3], 0.0f), z3);

            // split to fp16 hi + lo (packed RTZ converts)
            const p2_t hi01 = __builtin_amdgcn_cvt_pkrtz(hs0, hs1);
            const p2_t hi23 = __builtin_amdgcn_cvt_pkrtz(hs2, hs3);
            const float l0 = hs0 - (float)hi01[0];
            const float l1 = hs1 - (float)hi01[1];
            const float l2 = hs2 - (float)hi23[0];
            const float l3 = hs3 - (float)hi23[1];
            const p2_t lo01 = __builtin_amdgcn_cvt_pkrtz(l0, l1);
            const p2_t lo23 = __builtin_amdgcn_cvt_pkrtz(l2, l3);
            b_hi[0] = (_Float16)hi01[0]; b_hi[1] = (_Float16)hi01[1];
            b_hi[2] = (_Float16)hi23[0]; b_hi[3] = (_Float16)hi23[1];
            b_lo[0] = (_Float16)lo01[0]; b_lo[1] = (_Float16)lo01[1];
            b_lo[2] = (_Float16)lo23[0]; b_lo[3] = (_Float16)lo23[1];
        }
    }

    // epilogue: gather h via LDS, then the 10x10 output projection
    __shared__ float hsh[16][17];
    hsh[m][n0 + 0] = hs0;
    hsh[m][n0 + 1] = hs1;
    hsh[m][n0 + 2] = hs2;
    hsh[m][n0 + 3] = hs3;
    __syncthreads();   // single-wave block: lgkmcnt wait only
#pragma unroll
    for (int jo = 0; jo < 3; ++jo) {
        const int o = q + 4 * jo;
        if (o < H) {
            float acc = lb[o];
#pragma unroll
            for (int jj = 0; jj < H; ++jj)
                acc = fmaf(hsh[m][jj], lW[o * H + jj], acc);
            out[(size_t)batch * H + o] = acc;
        }
    }
}

extern "C" void kernel_launch(void* const* d_in, const int* in_sizes, int n_in,
                              void* d_out, int out_size, void* d_ws, size_t ws_size,
                              hipStream_t stream) {
    const float* inputs = (const float*)d_in[0];  // [8192, 2048, 2]
    const float* A      = (const float*)d_in[1];  // [10, 10]
    const float* W_in   = (const float*)d_in[2];  // [10, 2]
    const float* b_mod  = (const float*)d_in[3];  // [10]
    const float* lin_W  = (const float*)d_in[4];  // [10, 10]
    const float* lin_b  = (const float*)d_in[5];  // [10]
    float* out = (float*)d_out;                   // [8192, 10]
    float* Bpad = (float*)d_ws;                   // 256 floats scratch

    expm_kernel<<<1, 128, 0, stream>>>(A, Bpad);
    rnn_kernel<<<BATCH / 16, 64, 0, stream>>>(inputs, Bpad, W_in, b_mod,
                                              lin_W, lin_b, out);
}